// Round 16
// baseline (245.690 us; speedup 1.0000x reference)
//
#include <hip/hip_runtime.h>
#include <hip/hip_bf16.h>
#include <hip/hip_cooperative_groups.h>

namespace cg = cooperative_groups;

#define B_ 32
#define N_ 4096
#define C_ 256
#define W_ 64
#define OUT_ 512
#define EPS_ 1e-5f

typedef __attribute__((ext_vector_type(8))) short short8;
typedef __attribute__((ext_vector_type(4))) float floatx4;

// workspace layout (bytes)
#define WT_OFF     0                    // wt bf16 [b][w][n] = 16 MB
#define AGGB_OFF   16777216             // aggB bf16 [b][k=c*64+w] = 1 MB
#define PART_OFF   17825792             // k3 partials f32 [kb<32][o*32+b] = 2 MB
#define WS_NEEDED  19922944

#define GLOAD_LDS16(g, l)                                                  \
  __builtin_amdgcn_global_load_lds(                                        \
      (const __attribute__((address_space(1))) void*)(g),                  \
      (__attribute__((address_space(3))) void*)(l), 16, 0, 0)

__device__ __forceinline__ ushort f2bf(float f) {
  unsigned u = __builtin_bit_cast(unsigned, f);
  unsigned r = (u + 0x7fffu + ((u >> 16) & 1u)) >> 16;  // RTNE
  return (ushort)r;
}
__device__ __forceinline__ ushort f2bh(float f) {
  return (ushort)((__builtin_bit_cast(unsigned, f) + 0x8000u) >> 16);
}
__device__ __forceinline__ unsigned pk2h(float a, float b) {
  unsigned ua = __builtin_bit_cast(unsigned, a);
  unsigned ub = __builtin_bit_cast(unsigned, b);
  return ((ua + 0x8000u) >> 16) | ((ub + 0x8000u) & 0xffff0000u);
}

// ==================== device-side phase bodies (shared by fused & fallback) ====================

struct P1Shared {
  ushort h[256 * 72];
  ushort w2[64 * 72];
  ushort w3[64 * 72];
  float w1l[192];
  float b1l[64];
  float b2[64];
  float b3[64];
};
struct P2Shared {
  float A[4][32 * 128];    // 64 KB
  ushort Bv[4][64 * 128];  // 64 KB
};

// ---- k1 weight-fuse (all 256 threads) ----
__device__ __forceinline__ void k1_fuse_weights(
    P1Shared& sm, int t,
    const float* __restrict__ w1, const float* __restrict__ b1,
    const float* __restrict__ g1, const float* __restrict__ be1,
    const float* __restrict__ m1, const float* __restrict__ v1,
    const float* __restrict__ w2, const float* __restrict__ b2,
    const float* __restrict__ g2, const float* __restrict__ be2,
    const float* __restrict__ m2, const float* __restrict__ v2,
    const float* __restrict__ w3, const float* __restrict__ b3,
    const float* __restrict__ g3, const float* __restrict__ be3,
    const float* __restrict__ m3, const float* __restrict__ v3) {
  const int row = t >> 2, q = t & 3;
  const float s2 = g2[row] * rsqrtf(v2[row] + EPS_);
  const float s3 = g3[row] * rsqrtf(v3[row] + EPS_);
  unsigned* w2row = (unsigned*)&sm.w2[row * 72];
  unsigned* w3row = (unsigned*)&sm.w3[row * 72];
#pragma unroll
  for (int j = 0; j < 4; ++j) {
    float4 a = *(const float4*)&w2[row * 64 + q * 16 + j * 4];
    w2row[q * 8 + j * 2]     = pk2h(a.x * s2, a.y * s2);
    w2row[q * 8 + j * 2 + 1] = pk2h(a.z * s2, a.w * s2);
    float4 c = *(const float4*)&w3[row * 64 + q * 16 + j * 4];
    w3row[q * 8 + j * 2]     = pk2h(c.x * s3, c.y * s3);
    w3row[q * 8 + j * 2 + 1] = pk2h(c.z * s3, c.w * s3);
  }
  if (q == 0) {
    w2row[32] = 0; w2row[33] = 0; w2row[34] = 0; w2row[35] = 0;
    w3row[32] = 0; w3row[33] = 0; w3row[34] = 0; w3row[35] = 0;
  }
  if (t < 64) {
    float s1 = g1[t] * rsqrtf(v1[t] + EPS_);
#pragma unroll
    for (int j = 0; j < 3; ++j) sm.w1l[t * 3 + j] = w1[t * 3 + j] * s1;
    sm.b1l[t] = (b1[t] - m1[t]) * s1 + be1[t];
    sm.b2[t] = (b2[t] - m2[t]) * (g2[t] * rsqrtf(v2[t] + EPS_)) + be2[t];
    sm.b3[t] = (b3[t] - m3[t]) * (g3[t] * rsqrtf(v3[t] + EPS_)) + be3[t];
  }
}

// ---- k1 per-(b,n0)-tile body; expects fused weights in sm, syncthreads'd ----
__device__ __forceinline__ void k1_tile(P1Shared& sm, int t, int b, int n0,
                                        const float* __restrict__ xyz,
                                        ushort* __restrict__ wt) {
  const float* xp = xyz + ((size_t)b * N_ + (n0 + t)) * 3;
  float x0 = xp[0], x1 = xp[1], x2 = xp[2];
  unsigned* hrow = (unsigned*)&sm.h[t * 72];
#pragma unroll 4
  for (int cp = 0; cp < 32; ++cp) {
    int c0 = cp * 2, c1 = cp * 2 + 1;
    float a0 = fmaxf(sm.b1l[c0] + sm.w1l[c0 * 3] * x0 + sm.w1l[c0 * 3 + 1] * x1 + sm.w1l[c0 * 3 + 2] * x2, 0.f);
    float a1 = fmaxf(sm.b1l[c1] + sm.w1l[c1 * 3] * x0 + sm.w1l[c1 * 3 + 1] * x1 + sm.w1l[c1 * 3 + 2] * x2, 0.f);
    hrow[cp] = pk2h(a0, a1);
  }
  __syncthreads();

  const int wv = t >> 6, lane = t & 63;
  const int lrow = lane & 15, lk = lane >> 4;

  floatx4 acc[4][4];
#pragma unroll
  for (int mt = 0; mt < 4; ++mt)
#pragma unroll
    for (int nt = 0; nt < 4; ++nt) acc[mt][nt] = (floatx4){0.f, 0.f, 0.f, 0.f};

#pragma unroll
  for (int ks = 0; ks < 2; ++ks) {
    short8 afr[4], bfr[4];
#pragma unroll
    for (int mt = 0; mt < 4; ++mt)
      afr[mt] = *(const short8*)&sm.h[(wv * 64 + mt * 16 + lrow) * 72 + ks * 32 + lk * 8];
#pragma unroll
    for (int nt = 0; nt < 4; ++nt)
      bfr[nt] = *(const short8*)&sm.w2[(nt * 16 + lrow) * 72 + ks * 32 + lk * 8];
#pragma unroll
    for (int mt = 0; mt < 4; ++mt)
#pragma unroll
      for (int nt = 0; nt < 4; ++nt)
        acc[mt][nt] = __builtin_amdgcn_mfma_f32_16x16x32_bf16(afr[mt], bfr[nt], acc[mt][nt], 0, 0, 0);
  }
#pragma unroll
  for (int mt = 0; mt < 4; ++mt)
#pragma unroll
    for (int nt = 0; nt < 4; ++nt) {
      float bias = sm.b2[nt * 16 + lrow];
#pragma unroll
      for (int r = 0; r < 4; ++r) {
        float v = fmaxf(acc[mt][nt][r] + bias, 0.f);
        sm.h[(wv * 64 + mt * 16 + lk * 4 + r) * 72 + nt * 16 + lrow] = f2bh(v);
      }
    }

  floatx4 acc3[4][4];
#pragma unroll
  for (int mt = 0; mt < 4; ++mt)
#pragma unroll
    for (int nt = 0; nt < 4; ++nt) acc3[mt][nt] = (floatx4){0.f, 0.f, 0.f, 0.f};

#pragma unroll
  for (int ks = 0; ks < 2; ++ks) {
    short8 afr[4], bfr[4];
#pragma unroll
    for (int mt = 0; mt < 4; ++mt)
      afr[mt] = *(const short8*)&sm.h[(wv * 64 + mt * 16 + lrow) * 72 + ks * 32 + lk * 8];
#pragma unroll
    for (int nt = 0; nt < 4; ++nt)
      bfr[nt] = *(const short8*)&sm.w3[(nt * 16 + lrow) * 72 + ks * 32 + lk * 8];
#pragma unroll
    for (int mt = 0; mt < 4; ++mt)
#pragma unroll
      for (int nt = 0; nt < 4; ++nt)
        acc3[mt][nt] = __builtin_amdgcn_mfma_f32_16x16x32_bf16(afr[mt], bfr[nt], acc3[mt][nt], 0, 0, 0);
  }

  __syncthreads();
  unsigned* T = (unsigned*)sm.h;  // T[64 ch][132 u32]
#pragma unroll
  for (int mt = 0; mt < 4; ++mt)
#pragma unroll
    for (int nt = 0; nt < 4; ++nt) {
      float bias = sm.b3[nt * 16 + lrow];
      float v0 = fmaxf(acc3[mt][nt][0] + bias, 0.f);
      float v1 = fmaxf(acc3[mt][nt][1] + bias, 0.f);
      float v2 = fmaxf(acc3[mt][nt][2] + bias, 0.f);
      float v3 = fmaxf(acc3[mt][nt][3] + bias, 0.f);
      int ch = nt * 16 + lrow;
      int pp = (wv * 64 + mt * 16 + lk * 4) >> 1;
      T[ch * 132 + pp] = pk2h(v0, v1);
      T[ch * 132 + pp + 1] = pk2h(v2, v3);
    }
  __syncthreads();

  const int ch = t >> 2, q = t & 3;
  unsigned* wtu = (unsigned*)wt;
  size_t obase = ((size_t)(b * W_ + ch)) * (N_ / 2) + (n0 >> 1);
#pragma unroll
  for (int j = 0; j < 8; ++j) {
    int col = q * 4 + j * 16;
    uint4 vv = *(const uint4*)&T[ch * 132 + col];
    *(uint4*)&wtu[obase + col] = vv;
  }
  __syncthreads();  // protect sm.h reuse by the next tile iteration
}

// ---- k2 body (R12-proven 4-buffer counted-vmcnt pipeline), blockIdx passed in ----
__device__ __forceinline__ void k2_body(P2Shared& sm, int t, int blk,
                                        const float* __restrict__ feature,
                                        const ushort* __restrict__ wt,
                                        ushort* __restrict__ aggB) {
  const int wv = t >> 6, lane = t & 63;
  const int lrow = lane & 15, lk = lane >> 4;
  const int b = blk & 31;
  const int ct = blk >> 5;

  const float* fbase = feature + (size_t)(b * C_ + ct * 32) * N_;
  const ushort* wbase = wt + (size_t)(b * W_) * N_;

  const int rowA = (lane >> 5);
  const int colA = (lane & 31);
  const int rowB = (lane >> 4);
  const int colB = (lane & 15);

#define STAGE(buf, step)                                                          \
  do {                                                                            \
    _Pragma("unroll")                                                             \
    for (int q = 0; q < 4; ++q) {                                                 \
      int j = wv * 4 + q;                                                         \
      int ra = 2 * j + rowA;                                                      \
      int ga = colA ^ (ra & 7);                                                   \
      GLOAD_LDS16(fbase + (size_t)ra * N_ + (step) * 128 + ga * 4,                \
                  &sm.A[buf][j * 256 + lane * 4]);                                \
      int rb = 4 * j + rowB;                                                      \
      int gb = colB ^ (rb & 7);                                                   \
      GLOAD_LDS16(wbase + (size_t)rb * N_ + (step) * 128 + gb * 8,                \
                  &sm.Bv[buf][j * 512 + lane * 8]);                               \
    }                                                                             \
  } while (0)

  const int cg2 = wv >> 1, wg = wv & 1;
  const int r_c = cg2 * 16 + lrow;
  const int eA = r_c & 7;
  const int r_w0 = wg * 32 + lrow;
  const int eB0 = r_w0 & 7, eB1 = (r_w0 + 16) & 7;

  floatx4 acc[2];
  acc[0] = (floatx4){0.f, 0.f, 0.f, 0.f};
  acc[1] = (floatx4){0.f, 0.f, 0.f, 0.f};

  auto compute = [&](int cur) {
    const float* abuf = &sm.A[cur][r_c * 128];
    const ushort* bbuf0 = &sm.Bv[cur][r_w0 * 128];
    const ushort* bbuf1 = &sm.Bv[cur][(r_w0 + 16) * 128];
#pragma unroll
    for (int ksl = 0; ksl < 4; ++ksl) {
      const int p = ksl * 8 + lk * 2;
      float4 fa = *(const float4*)&abuf[((p) ^ eA) * 4];
      float4 fb = *(const float4*)&abuf[((p + 1) ^ eA) * 4];
      union { unsigned u[4]; short8 s8; } pa;
      pa.u[0] = pk2h(fa.x, fa.y);
      pa.u[1] = pk2h(fa.z, fa.w);
      pa.u[2] = pk2h(fb.x, fb.y);
      pa.u[3] = pk2h(fb.z, fb.w);
      const int g = ksl * 4 + lk;
      short8 b0 = *(const short8*)&bbuf0[(g ^ eB0) * 8];
      short8 b1 = *(const short8*)&bbuf1[(g ^ eB1) * 8];
      acc[0] = __builtin_amdgcn_mfma_f32_16x16x32_bf16(pa.s8, b0, acc[0], 0, 0, 0);
      acc[1] = __builtin_amdgcn_mfma_f32_16x16x32_bf16(pa.s8, b1, acc[1], 0, 0, 0);
    }
  };

#define WAIT_BAR(n) asm volatile("s_waitcnt vmcnt(" #n ")\n\ts_barrier" ::: "memory")

  STAGE(0, 0);
  STAGE(1, 1);
  STAGE(2, 2);
  for (int s4 = 0; s4 < 28; s4 += 4) {
    WAIT_BAR(16); STAGE(3, s4 + 3); compute(0);
    WAIT_BAR(16); STAGE(0, s4 + 4); compute(1);
    WAIT_BAR(16); STAGE(1, s4 + 5); compute(2);
    WAIT_BAR(16); STAGE(2, s4 + 6); compute(3);
  }
  WAIT_BAR(16); STAGE(3, 31); compute(0);
  WAIT_BAR(16); compute(1);
  WAIT_BAR(8);  compute(2);
  WAIT_BAR(0);  compute(3);
#undef STAGE
#undef WAIT_BAR

  const float sc = 1.f / 4096.f;
  ushort* dst = aggB + (size_t)b * 16384;
#pragma unroll
  for (int wt2 = 0; wt2 < 2; ++wt2)
#pragma unroll
    for (int r = 0; r < 4; ++r) {
      int c = ct * 32 + cg2 * 16 + lk * 4 + r;
      int w = wg * 32 + wt2 * 16 + lrow;
      dst[c * 64 + w] = f2bf(acc[wt2][r] * sc);
    }
}

// ---- k3 body (R12-proven) ----
__device__ __forceinline__ void k3_body(int t, int blk,
                                        const float* __restrict__ wf,
                                        const ushort* __restrict__ aggB,
                                        float* __restrict__ part) {
  const int wv = t >> 6, lane = t & 63;
  const int lrow = lane & 15, lk = lane >> 4;
  const int ot = blk >> 5;
  const int kb = blk & 31;
  const int o0 = ot * 64 + wv * 16;
  const int k0 = kb * 512;

  const float* wp = wf + (size_t)(o0 + lrow) * 16384 + k0 + lk * 8;
  const ushort* a0 = aggB + (size_t)lrow * 16384 + k0 + lk * 8;
  const ushort* a1 = a0 + (size_t)16 * 16384;

  floatx4 acc0 = {0.f, 0.f, 0.f, 0.f}, acc1 = {0.f, 0.f, 0.f, 0.f};
#pragma unroll 8
  for (int s = 0; s < 16; ++s) {
    float4 f0 = *(const float4*)(wp + s * 32);
    float4 f1 = *(const float4*)(wp + s * 32 + 4);
    short8 b0 = *(const short8*)(a0 + s * 32);
    short8 b1 = *(const short8*)(a1 + s * 32);
    union { unsigned u[4]; short8 s8; } pa;
    pa.u[0] = pk2h(f0.x, f0.y);
    pa.u[1] = pk2h(f0.z, f0.w);
    pa.u[2] = pk2h(f1.x, f1.y);
    pa.u[3] = pk2h(f1.z, f1.w);
    acc0 = __builtin_amdgcn_mfma_f32_16x16x32_bf16(pa.s8, b0, acc0, 0, 0, 0);
    acc1 = __builtin_amdgcn_mfma_f32_16x16x32_bf16(pa.s8, b1, acc1, 0, 0, 0);
  }

  float* dst = part + (size_t)kb * 16384;
#pragma unroll
  for (int r = 0; r < 4; ++r) {
    int o = o0 + lk * 4 + r;
    dst[o * 32 + lrow] = acc0[r];
    dst[o * 32 + 16 + lrow] = acc1[r];
  }
}

// ---- k4 body ----
__device__ __forceinline__ void k4_body(int i, const float* __restrict__ bf,
                                        const float* __restrict__ gf,
                                        const float* __restrict__ bef,
                                        const float* __restrict__ mf,
                                        const float* __restrict__ vf,
                                        const float* __restrict__ part,
                                        float* __restrict__ out) {
  int o = i >> 5, b = i & 31;
  float v = 0.f;
#pragma unroll
  for (int kb = 0; kb < 32; ++kb) v += part[(size_t)kb * 16384 + i];
  float s = gf[o] * rsqrtf(vf[o] + EPS_);
  float r = (v + bf[o] - mf[o]) * s + bef[o];
  out[b * OUT_ + o] = fmaxf(r, 0.f);
}

// ==================== fused cooperative kernel ====================
__global__ __launch_bounds__(256) void k_fused(
    const float* xyz, const float* feature,
    const float* w1, const float* b1, const float* g1, const float* be1,
    const float* m1, const float* v1,
    const float* w2, const float* b2, const float* g2, const float* be2,
    const float* m2, const float* v2,
    const float* w3, const float* b3, const float* g3, const float* be3,
    const float* m3, const float* v3,
    const float* wf, const float* bf, const float* gf, const float* bef,
    const float* mf, const float* vf,
    ushort* wt, ushort* aggB, float* part, float* out) {
  __shared__ union {
    P1Shared p1;
    P2Shared p2;
  } sm;
  cg::grid_group grid = cg::this_grid();
  const int t = threadIdx.x;
  const int blk = blockIdx.x;

  // ---- phase 1: WeightNet (2 virtual blocks per block) ----
  k1_fuse_weights(sm.p1, t, w1, b1, g1, be1, m1, v1,
                  w2, b2, g2, be2, m2, v2, w3, b3, g3, be3, m3, v3);
  __syncthreads();
#pragma unroll
  for (int it = 0; it < 2; ++it) {
    int vblk = blk * 2 + it;
    k1_tile(sm.p1, t, vblk >> 4, (vblk & 15) << 8, xyz, wt);
  }
  __threadfence();
  grid.sync();

  // ---- phase 2: agg GEMM ----
  k2_body(sm.p2, t, blk, feature, wt, aggB);
  __threadfence();
  grid.sync();

  // ---- phase 3: final GEMM partials ----
  k3_body(t, blk, wf, aggB, part);
  __threadfence();
  grid.sync();

  // ---- phase 4: reduce + BN + ReLU ----
  if (t < 64) k4_body(blk * 64 + t, bf, gf, bef, mf, vf, part, out);
}

// ==================== standalone fallback kernels ====================
__global__ __launch_bounds__(256) void k1_weightnet(
    const float* __restrict__ xyz,
    const float* __restrict__ w1, const float* __restrict__ b1,
    const float* __restrict__ g1, const float* __restrict__ be1,
    const float* __restrict__ m1, const float* __restrict__ v1,
    const float* __restrict__ w2, const float* __restrict__ b2,
    const float* __restrict__ g2, const float* __restrict__ be2,
    const float* __restrict__ m2, const float* __restrict__ v2,
    const float* __restrict__ w3, const float* __restrict__ b3,
    const float* __restrict__ g3, const float* __restrict__ be3,
    const float* __restrict__ m3, const float* __restrict__ v3,
    ushort* __restrict__ wt) {
  __shared__ P1Shared sm;
  const int t = threadIdx.x;
  const int blk = blockIdx.x;
  k1_fuse_weights(sm, t, w1, b1, g1, be1, m1, v1,
                  w2, b2, g2, be2, m2, v2, w3, b3, g3, be3, m3, v3);
  __syncthreads();
  k1_tile(sm, t, blk >> 4, (blk & 15) << 8, xyz, wt);
}

__global__ __launch_bounds__(256) void k2_agg(const float* __restrict__ feature,
                                              const ushort* __restrict__ wt,
                                              ushort* __restrict__ aggB) {
  __shared__ P2Shared sm;
  k2_body(sm, threadIdx.x, blockIdx.x, feature, wt, aggB);
}

__global__ __launch_bounds__(256) void k3_final(const float* __restrict__ wf,
                                                const ushort* __restrict__ aggB,
                                                float* __restrict__ part) {
  k3_body(threadIdx.x, blockIdx.x, wf, aggB, part);
}

__global__ __launch_bounds__(64) void k4_finalize(
    const float* __restrict__ bf, const float* __restrict__ gf,
    const float* __restrict__ bef, const float* __restrict__ mf,
    const float* __restrict__ vf, const float* __restrict__ part,
    float* __restrict__ out) {
  k4_body(blockIdx.x * 64 + threadIdx.x, bf, gf, bef, mf, vf, part, out);
}

extern "C" void kernel_launch(void* const* d_in, const int* in_sizes, int n_in,
                              void* d_out, int out_size, void* d_ws, size_t ws_size,
                              hipStream_t stream) {
  const float* xyz     = (const float*)d_in[0];
  const float* feature = (const float*)d_in[1];
  const float* w1 = (const float*)d_in[3];
  const float* b1 = (const float*)d_in[4];
  const float* g1 = (const float*)d_in[5];
  const float* be1 = (const float*)d_in[6];
  const float* m1 = (const float*)d_in[7];
  const float* v1 = (const float*)d_in[8];
  const float* w2 = (const float*)d_in[9];
  const float* b2 = (const float*)d_in[10];
  const float* g2 = (const float*)d_in[11];
  const float* be2 = (const float*)d_in[12];
  const float* m2 = (const float*)d_in[13];
  const float* v2 = (const float*)d_in[14];
  const float* w3 = (const float*)d_in[15];
  const float* b3 = (const float*)d_in[16];
  const float* g3 = (const float*)d_in[17];
  const float* be3 = (const float*)d_in[18];
  const float* m3 = (const float*)d_in[19];
  const float* v3 = (const float*)d_in[20];
  const float* wf = (const float*)d_in[21];
  const float* bf = (const float*)d_in[22];
  const float* gf = (const float*)d_in[23];
  const float* bef = (const float*)d_in[24];
  const float* mf = (const float*)d_in[25];
  const float* vf = (const float*)d_in[26];

  char* ws = (char*)d_ws;
  if (ws_size < (size_t)WS_NEEDED) return;
  ushort* wt   = (ushort*)(ws + WT_OFF);
  ushort* aggB = (ushort*)(ws + AGGB_OFF);
  float*  part = (float*)(ws + PART_OFF);
  float*  outp = (float*)d_out;

  void* args[] = {
      (void*)&xyz, (void*)&feature,
      (void*)&w1, (void*)&b1, (void*)&g1, (void*)&be1, (void*)&m1, (void*)&v1,
      (void*)&w2, (void*)&b2, (void*)&g2, (void*)&be2, (void*)&m2, (void*)&v2,
      (void*)&w3, (void*)&b3, (void*)&g3, (void*)&be3, (void*)&m3, (void*)&v3,
      (void*)&wf, (void*)&bf, (void*)&gf, (void*)&bef, (void*)&mf, (void*)&vf,
      (void*)&wt, (void*)&aggB, (void*)&part, (void*)&outp};

  hipError_t e = hipLaunchCooperativeKernel((const void*)k_fused, dim3(256),
                                            dim3(256), args, 0, stream);
  if (e != hipSuccess) {
    // fallback: proven 4-kernel path (R15)
    k1_weightnet<<<512, 256, 0, stream>>>(xyz,
                                          w1, b1, g1, be1, m1, v1,
                                          w2, b2, g2, be2, m2, v2,
                                          w3, b3, g3, be3, m3, v3, wt);
    k2_agg<<<256, 256, 0, stream>>>(feature, wt, aggB);
    k3_final<<<256, 256, 0, stream>>>(wf, aggB, part);
    k4_finalize<<<256, 64, 0, stream>>>(bf, gf, bef, mf, vf, part, outp);
  }
}

// Round 17
// 58.420 us; speedup vs baseline: 4.2056x; 4.2056x over previous
//
#include <hip/hip_runtime.h>
#include <hip/hip_bf16.h>

#define B_ 32
#define N_ 4096
#define C_ 256
#define W_ 64
#define OUT_ 512
#define EPS_ 1e-5f

typedef __attribute__((ext_vector_type(8))) short short8;
typedef __attribute__((ext_vector_type(4))) float floatx4;

// workspace layout (bytes)
#define WT_OFF     0                    // wt bf16 [b][w][n] = 16 MB
#define AGGB_OFF   16777216             // aggB bf16 [b][k=c*64+w] = 1 MB
#define PART_OFF   17825792             // k3 partials f32 [kb<32][o*32+b] = 2 MB
#define WS_NEEDED  19922944

#define GLOAD_LDS16(g, l)                                                  \
  __builtin_amdgcn_global_load_lds(                                        \
      (const __attribute__((address_space(1))) void*)(g),                  \
      (__attribute__((address_space(3))) void*)(l), 16, 0, 0)

__device__ __forceinline__ ushort f2bf(float f) {
  unsigned u = __builtin_bit_cast(unsigned, f);
  unsigned r = (u + 0x7fffu + ((u >> 16) & 1u)) >> 16;  // RTNE
  return (ushort)r;
}
// round-half-up (5 VALU vs 9; bias ties-only ~2^-17 rel) — validated in k2/k3
__device__ __forceinline__ ushort f2bh(float f) {
  return (ushort)((__builtin_bit_cast(unsigned, f) + 0x8000u) >> 16);
}
__device__ __forceinline__ unsigned pk2(float a, float b) {
  return (unsigned)f2bf(a) | ((unsigned)f2bf(b) << 16);
}
__device__ __forceinline__ unsigned pk2h(float a, float b) {
  unsigned ua = __builtin_bit_cast(unsigned, a);
  unsigned ub = __builtin_bit_cast(unsigned, b);
  return ((ua + 0x8000u) >> 16) | ((ub + 0x8000u) & 0xffff0000u);
}

// ---------------- K1: fuse BN + WeightNet (layer1 scalar, layers 2/3 MFMA) ----------------
__global__ __launch_bounds__(256) void k1_weightnet(
    const float* __restrict__ xyz,
    const float* __restrict__ w1, const float* __restrict__ b1,
    const float* __restrict__ g1, const float* __restrict__ be1,
    const float* __restrict__ m1, const float* __restrict__ v1,
    const float* __restrict__ w2, const float* __restrict__ b2,
    const float* __restrict__ g2, const float* __restrict__ be2,
    const float* __restrict__ m2, const float* __restrict__ v2,
    const float* __restrict__ w3, const float* __restrict__ b3,
    const float* __restrict__ g3, const float* __restrict__ be3,
    const float* __restrict__ m3, const float* __restrict__ v3,
    ushort* __restrict__ wt) {
  __shared__ __align__(16) ushort h_lds[256 * 72];   // reused as T[64][132] u32
  __shared__ __align__(16) ushort w2_lds[64 * 72];
  __shared__ __align__(16) ushort w3_lds[64 * 72];
  __shared__ float w1l[192];
  __shared__ float b1l[64];
  __shared__ float b2_lds[64];
  __shared__ float b3_lds[64];

  const int t = threadIdx.x;
  const int blk = blockIdx.x;
  const int b = blk >> 4;
  const int n0 = (blk & 15) << 8;

  // ---- xyz load issued FIRST: its HBM latency overlaps the fuse phase ----
  const int n = n0 + t;
  const float* xp = xyz + ((size_t)b * N_ + n) * 3;
  float x0 = xp[0], x1 = xp[1], x2 = xp[2];

  // ---- per-block BN fusing, parallel across all 256 threads ----
  {
    const int row = t >> 2, q = t & 3;
    const float s2 = g2[row] * rsqrtf(v2[row] + EPS_);
    const float s3 = g3[row] * rsqrtf(v3[row] + EPS_);
    unsigned* w2row = (unsigned*)&w2_lds[row * 72];
    unsigned* w3row = (unsigned*)&w3_lds[row * 72];
#pragma unroll
    for (int j = 0; j < 4; ++j) {
      float4 a = *(const float4*)&w2[row * 64 + q * 16 + j * 4];
      w2row[q * 8 + j * 2]     = pk2h(a.x * s2, a.y * s2);
      w2row[q * 8 + j * 2 + 1] = pk2h(a.z * s2, a.w * s2);
      float4 c = *(const float4*)&w3[row * 64 + q * 16 + j * 4];
      w3row[q * 8 + j * 2]     = pk2h(c.x * s3, c.y * s3);
      w3row[q * 8 + j * 2 + 1] = pk2h(c.z * s3, c.w * s3);
    }
    if (q == 0) {
      w2row[32] = 0; w2row[33] = 0; w2row[34] = 0; w2row[35] = 0;
      w3row[32] = 0; w3row[33] = 0; w3row[34] = 0; w3row[35] = 0;
    }
    if (t < 64) {
      float s1 = g1[t] * rsqrtf(v1[t] + EPS_);
#pragma unroll
      for (int j = 0; j < 3; ++j) w1l[t * 3 + j] = w1[t * 3 + j] * s1;
      b1l[t] = (b1[t] - m1[t]) * s1 + be1[t];
      b2_lds[t] = (b2[t] - m2[t]) * (g2[t] * rsqrtf(v2[t] + EPS_)) + be2[t];
      b3_lds[t] = (b3[t] - m3[t]) * (g3[t] * rsqrtf(v3[t] + EPS_)) + be3[t];
    }
  }
  __syncthreads();

  // ---- layer 1 (K=3), one point per thread, h1 bf16 -> LDS ----
  unsigned* hrow = (unsigned*)&h_lds[t * 72];
#pragma unroll 4
  for (int cp = 0; cp < 32; ++cp) {
    int c0 = cp * 2, c1 = cp * 2 + 1;
    float a0 = fmaxf(b1l[c0] + w1l[c0 * 3] * x0 + w1l[c0 * 3 + 1] * x1 + w1l[c0 * 3 + 2] * x2, 0.f);
    float a1 = fmaxf(b1l[c1] + w1l[c1 * 3] * x0 + w1l[c1 * 3 + 1] * x1 + w1l[c1 * 3 + 2] * x2, 0.f);
    hrow[cp] = pk2h(a0, a1);
  }
  __syncthreads();

  const int wv = t >> 6, lane = t & 63;
  const int lrow = lane & 15, lk = lane >> 4;

  floatx4 acc[4][4];
#pragma unroll
  for (int mt = 0; mt < 4; ++mt)
#pragma unroll
    for (int nt = 0; nt < 4; ++nt) acc[mt][nt] = (floatx4){0.f, 0.f, 0.f, 0.f};

#pragma unroll
  for (int ks = 0; ks < 2; ++ks) {
    short8 afr[4], bfr[4];
#pragma unroll
    for (int mt = 0; mt < 4; ++mt)
      afr[mt] = *(const short8*)&h_lds[(wv * 64 + mt * 16 + lrow) * 72 + ks * 32 + lk * 8];
#pragma unroll
    for (int nt = 0; nt < 4; ++nt)
      bfr[nt] = *(const short8*)&w2_lds[(nt * 16 + lrow) * 72 + ks * 32 + lk * 8];
#pragma unroll
    for (int mt = 0; mt < 4; ++mt)
#pragma unroll
      for (int nt = 0; nt < 4; ++nt)
        acc[mt][nt] = __builtin_amdgcn_mfma_f32_16x16x32_bf16(afr[mt], bfr[nt], acc[mt][nt], 0, 0, 0);
  }
#pragma unroll
  for (int mt = 0; mt < 4; ++mt)
#pragma unroll
    for (int nt = 0; nt < 4; ++nt) {
      float bias = b2_lds[nt * 16 + lrow];
#pragma unroll
      for (int r = 0; r < 4; ++r) {
        float v = fmaxf(acc[mt][nt][r] + bias, 0.f);
        h_lds[(wv * 64 + mt * 16 + lk * 4 + r) * 72 + nt * 16 + lrow] = f2bh(v);
      }
    }

  floatx4 acc3[4][4];
#pragma unroll
  for (int mt = 0; mt < 4; ++mt)
#pragma unroll
    for (int nt = 0; nt < 4; ++nt) acc3[mt][nt] = (floatx4){0.f, 0.f, 0.f, 0.f};

#pragma unroll
  for (int ks = 0; ks < 2; ++ks) {
    short8 afr[4], bfr[4];
#pragma unroll
    for (int mt = 0; mt < 4; ++mt)
      afr[mt] = *(const short8*)&h_lds[(wv * 64 + mt * 16 + lrow) * 72 + ks * 32 + lk * 8];
#pragma unroll
    for (int nt = 0; nt < 4; ++nt)
      bfr[nt] = *(const short8*)&w3_lds[(nt * 16 + lrow) * 72 + ks * 32 + lk * 8];
#pragma unroll
    for (int mt = 0; mt < 4; ++mt)
#pragma unroll
      for (int nt = 0; nt < 4; ++nt)
        acc3[mt][nt] = __builtin_amdgcn_mfma_f32_16x16x32_bf16(afr[mt], bfr[nt], acc3[mt][nt], 0, 0, 0);
  }

  __syncthreads();
  unsigned* T = (unsigned*)h_lds;  // T[64 ch][132 u32]
#pragma unroll
  for (int mt = 0; mt < 4; ++mt)
#pragma unroll
    for (int nt = 0; nt < 4; ++nt) {
      float bias = b3_lds[nt * 16 + lrow];
      float v0 = fmaxf(acc3[mt][nt][0] + bias, 0.f);
      float v1 = fmaxf(acc3[mt][nt][1] + bias, 0.f);
      float v2 = fmaxf(acc3[mt][nt][2] + bias, 0.f);
      float v3 = fmaxf(acc3[mt][nt][3] + bias, 0.f);
      int ch = nt * 16 + lrow;
      int pp = (wv * 64 + mt * 16 + lk * 4) >> 1;
      T[ch * 132 + pp] = pk2h(v0, v1);
      T[ch * 132 + pp + 1] = pk2h(v2, v3);
    }
  __syncthreads();

  const int ch = t >> 2, q = t & 3;
  unsigned* wtu = (unsigned*)wt;
  size_t obase = ((size_t)(b * W_ + ch)) * (N_ / 2) + (n0 >> 1);
#pragma unroll
  for (int j = 0; j < 8; ++j) {
    int col = q * 4 + j * 16;
    uint4 vv = *(const uint4*)&T[ch * 132 + col];
    *(uint4*)&wtu[obase + col] = vv;
  }
}

// ---------------- K2: aggB[b][c*64+w] (bf16) = sum_n feat[b][c][n]/N * wt[b][w][n] ----------------
// 256 blocks = ct*32 + b (1 block/CU); 4 waves; tile 32c x 64w; K=4096 in 32 steps of 128.
// 4-buffer global_load_lds pipeline, SINGLE barrier per step (R12-proven).
__global__ __launch_bounds__(256) void k2_agg(const float* __restrict__ feature,
                                              const ushort* __restrict__ wt,
                                              ushort* __restrict__ aggB) {
  __shared__ __align__(16) float A_lds[4][32 * 128];   // 64 KB
  __shared__ __align__(16) ushort B_lds[4][64 * 128];  // 64 KB

  const int t = threadIdx.x;
  const int wv = t >> 6, lane = t & 63;
  const int lrow = lane & 15, lk = lane >> 4;
  const int blk = blockIdx.x;
  const int b = blk & 31;
  const int ct = blk >> 5;     // same-b blocks at stride 32 -> same XCD (wt L2 reuse)

  const float* fbase = feature + (size_t)(b * C_ + ct * 32) * N_;
  const ushort* wbase = wt + (size_t)(b * W_) * N_;

  const int rowA = (lane >> 5);            // + 2*j
  const int colA = (lane & 31);            // granule (16B) within A row (of 32)
  const int rowB = (lane >> 4);            // + 4*j
  const int colB = (lane & 15);            // granule within B row (of 16)

  // 8 global_load_lds per wave per STAGE
#define STAGE(buf, step)                                                          \
  do {                                                                            \
    _Pragma("unroll")                                                             \
    for (int q = 0; q < 4; ++q) {                                                 \
      int j = wv * 4 + q;                                                         \
      int ra = 2 * j + rowA;                                                      \
      int ga = colA ^ (ra & 7); /* inverse-swizzled source granule */             \
      GLOAD_LDS16(fbase + (size_t)ra * N_ + (step) * 128 + ga * 4,                \
                  &A_lds[buf][j * 256 + lane * 4]);                               \
      int rb = 4 * j + rowB;                                                      \
      int gb = colB ^ (rb & 7);                                                   \
      GLOAD_LDS16(wbase + (size_t)rb * N_ + (step) * 128 + gb * 8,                \
                  &B_lds[buf][j * 512 + lane * 8]);                               \
    }                                                                             \
  } while (0)

  const int cg = wv >> 1, wg = wv & 1;     // wave quadrant: c-half x w-half
  const int r_c = cg * 16 + lrow;
  const int eA = r_c & 7;
  const int r_w0 = wg * 32 + lrow;
  const int eB0 = r_w0 & 7, eB1 = (r_w0 + 16) & 7;

  floatx4 acc[2];
  acc[0] = (floatx4){0.f, 0.f, 0.f, 0.f};
  acc[1] = (floatx4){0.f, 0.f, 0.f, 0.f};

  auto compute = [&](int cur) {
    const float* abuf = &A_lds[cur][r_c * 128];
    const ushort* bbuf0 = &B_lds[cur][r_w0 * 128];
    const ushort* bbuf1 = &B_lds[cur][(r_w0 + 16) * 128];
#pragma unroll
    for (int ksl = 0; ksl < 4; ++ksl) {
      const int p = ksl * 8 + lk * 2;
      float4 fa = *(const float4*)&abuf[((p) ^ eA) * 4];
      float4 fb = *(const float4*)&abuf[((p + 1) ^ eA) * 4];
      union { unsigned u[4]; short8 s8; } pa;
      pa.u[0] = pk2h(fa.x, fa.y);
      pa.u[1] = pk2h(fa.z, fa.w);
      pa.u[2] = pk2h(fb.x, fb.y);
      pa.u[3] = pk2h(fb.z, fb.w);
      const int g = ksl * 4 + lk;
      short8 b0 = *(const short8*)&bbuf0[(g ^ eB0) * 8];
      short8 b1 = *(const short8*)&bbuf1[(g ^ eB1) * 8];
      acc[0] = __builtin_amdgcn_mfma_f32_16x16x32_bf16(pa.s8, b0, acc[0], 0, 0, 0);
      acc[1] = __builtin_amdgcn_mfma_f32_16x16x32_bf16(pa.s8, b1, acc[1], 0, 0, 0);
    }
  };

#define WAIT_BAR(n) asm volatile("s_waitcnt vmcnt(" #n ")\n\ts_barrier" ::: "memory")

  STAGE(0, 0);
  STAGE(1, 1);
  STAGE(2, 2);
  // steps 0..27 in groups of 4 (buffer indices static)
  for (int s4 = 0; s4 < 28; s4 += 4) {
    WAIT_BAR(16); STAGE(3, s4 + 3); compute(0);
    WAIT_BAR(16); STAGE(0, s4 + 4); compute(1);
    WAIT_BAR(16); STAGE(1, s4 + 5); compute(2);
    WAIT_BAR(16); STAGE(2, s4 + 6); compute(3);
  }
  // tail: steps 28..31 (step 31 staged in s=28's slot)
  WAIT_BAR(16); STAGE(3, 31); compute(0);
  WAIT_BAR(16); compute(1);
  WAIT_BAR(8);  compute(2);
  WAIT_BAR(0);  compute(3);
#undef STAGE
#undef WAIT_BAR

  // D: row = c-frag row = lk*4+r, col = w = lrow
  const float sc = 1.f / 4096.f;
  ushort* dst = aggB + (size_t)b * 16384;
#pragma unroll
  for (int wt2 = 0; wt2 < 2; ++wt2)
#pragma unroll
    for (int r = 0; r < 4; ++r) {
      int c = ct * 32 + cg * 16 + lk * 4 + r;
      int w = wg * 32 + wt2 * 16 + lrow;
      dst[c * 64 + w] = f2bf(acc[wt2][r] * sc);
    }
}

// ---------------- K3: part[kb][o*32+b] = sum_{k-chunk} wf[o][k] * aggB[b][k]  (MFMA) ----------------
// R12-proven: 256 blocks = 8 o-tiles x 32 k-splits; wave: 16 o rows, 32 b, K-chunk 512.
__global__ __launch_bounds__(256) void k3_final(const float* __restrict__ wf,
                                                const ushort* __restrict__ aggB,
                                                float* __restrict__ part) {
  const int t = threadIdx.x;
  const int wv = t >> 6, lane = t & 63;
  const int lrow = lane & 15, lk = lane >> 4;
  const int ot = blockIdx.x >> 5;
  const int kb = blockIdx.x & 31;
  const int o0 = ot * 64 + wv * 16;
  const int k0 = kb * 512;

  const float* wp = wf + (size_t)(o0 + lrow) * 16384 + k0 + lk * 8;
  const ushort* a0 = aggB + (size_t)lrow * 16384 + k0 + lk * 8;
  const ushort* a1 = a0 + (size_t)16 * 16384;

  floatx4 acc0 = {0.f, 0.f, 0.f, 0.f}, acc1 = {0.f, 0.f, 0.f, 0.f};
#pragma unroll 8
  for (int s = 0; s < 16; ++s) {
    float4 f0 = *(const float4*)(wp + s * 32);
    float4 f1 = *(const float4*)(wp + s * 32 + 4);
    short8 b0 = *(const short8*)(a0 + s * 32);
    short8 b1 = *(const short8*)(a1 + s * 32);
    union { unsigned u[4]; short8 s8; } pa;
    pa.u[0] = pk2h(f0.x, f0.y);
    pa.u[1] = pk2h(f0.z, f0.w);
    pa.u[2] = pk2h(f1.x, f1.y);
    pa.u[3] = pk2h(f1.z, f1.w);
    acc0 = __builtin_amdgcn_mfma_f32_16x16x32_bf16(pa.s8, b0, acc0, 0, 0, 0);
    acc1 = __builtin_amdgcn_mfma_f32_16x16x32_bf16(pa.s8, b1, acc1, 0, 0, 0);
  }

  float* dst = part + (size_t)kb * 16384;
#pragma unroll
  for (int r = 0; r < 4; ++r) {
    int o = o0 + lk * 4 + r;
    dst[o * 32 + lrow] = acc0[r];
    dst[o * 32 + 16 + lrow] = acc1[r];
  }
}

// ---------------- K4: reduce partials + final BN + ReLU ----------------
__global__ __launch_bounds__(64) void k4_finalize(
    const float* __restrict__ bf, const float* __restrict__ gf,
    const float* __restrict__ bef, const float* __restrict__ mf,
    const float* __restrict__ vf, const float* __restrict__ part,
    float* __restrict__ out) {
  int i = blockIdx.x * 64 + threadIdx.x;  // 0..16383
  int o = i >> 5, b = i & 31;
  float v = 0.f;
#pragma unroll
  for (int kb = 0; kb < 32; ++kb) v += part[(size_t)kb * 16384 + i];
  float s = gf[o] * rsqrtf(vf[o] + EPS_);
  float r = (v + bf[o] - mf[o]) * s + bef[o];
  out[b * OUT_ + o] = fmaxf(r, 0.f);
}

extern "C" void kernel_launch(void* const* d_in, const int* in_sizes, int n_in,
                              void* d_out, int out_size, void* d_ws, size_t ws_size,
                              hipStream_t stream) {
  const float* xyz     = (const float*)d_in[0];
  const float* feature = (const float*)d_in[1];
  const float* w1 = (const float*)d_in[3];
  const float* b1 = (const float*)d_in[4];
  const float* g1 = (const float*)d_in[5];
  const float* be1 = (const float*)d_in[6];
  const float* m1 = (const float*)d_in[7];
  const float* v1 = (const float*)d_in[8];
  const float* w2 = (const float*)d_in[9];
  const float* b2 = (const float*)d_in[10];
  const float* g2 = (const float*)d_in[11];
  const float* be2 = (const float*)d_in[12];
  const float* m2 = (const float*)d_in[13];
  const float* v2 = (const float*)d_in[14];
  const float* w3 = (const float*)d_in[15];
  const float* b3 = (const float*)d_in[16];
  const float* g3 = (const float*)d_in[17];
  const float* be3 = (const float*)d_in[18];
  const float* m3 = (const float*)d_in[19];
  const float* v3 = (const float*)d_in[20];
  const float* wf = (const float*)d_in[21];
  const float* bf = (const float*)d_in[22];
  const float* gf = (const float*)d_in[23];
  const float* bef = (const float*)d_in[24];
  const float* mf = (const float*)d_in[25];
  const float* vf = (const float*)d_in[26];

  char* ws = (char*)d_ws;
  if (ws_size < (size_t)WS_NEEDED) return;
  ushort* wt   = (ushort*)(ws + WT_OFF);
  ushort* aggB = (ushort*)(ws + AGGB_OFF);
  float*  part = (float*)(ws + PART_OFF);

  k1_weightnet<<<512, 256, 0, stream>>>(xyz,
                                        w1, b1, g1, be1, m1, v1,
                                        w2, b2, g2, be2, m2, v2,
                                        w3, b3, g3, be3, m3, v3, wt);
  k2_agg<<<256, 256, 0, stream>>>(feature, wt, aggB);
  k3_final<<<256, 256, 0, stream>>>(wf, aggB, part);
  k4_finalize<<<256, 64, 0, stream>>>(bf, gf, bef, mf, vf, part, (float*)d_out);
}